// Round 1
// baseline (1247.169 us; speedup 1.0000x reference)
//
#include <hip/hip_runtime.h>
#include <stdint.h>

// Set Transformer forward on gfx950.
// N_KEYS=2048, EMB=768, HID=512, HEADS=8, head_dim=64, N_OUT=7.
// All GEMMs/attention in bf16 MFMA (16x16x32), fp32 accumulation.
// Correctness budget: threshold = 2% of max|ref| -> bf16 is safe.

#define HID 512
#define EMBD 768
#define NCTX 2048
#define HD 64

typedef __attribute__((ext_vector_type(8))) short v8s;   // 8 x bf16
typedef __attribute__((ext_vector_type(4))) float v4f;   // MFMA accumulator

#define MFMA(a, b, c) __builtin_amdgcn_mfma_f32_16x16x32_bf16((a), (b), (c), 0, 0, 0)

__device__ __forceinline__ short f2bf(float f) {
  uint32_t u = __builtin_bit_cast(uint32_t, f);
  uint32_t r = (u + 0x7FFFu + ((u >> 16) & 1u)) >> 16;  // RNE
  return (short)r;
}
__device__ __forceinline__ float bf2f(short s) {
  uint32_t u = ((uint32_t)(uint16_t)s) << 16;
  return __builtin_bit_cast(float, u);
}
__device__ __forceinline__ v8s ldbf8(const short* p) { return *(const v8s*)p; }

// ---------------- weight f32 -> bf16 pre-conversion (single packed kernel) ----
struct ConvDesc {
  const float* src[12];
  unsigned cum[13];  // dst offsets (shorts); dst region is contiguous in same order
};

__global__ void k_convert(ConvDesc d, short* __restrict__ dst) {
  unsigned i = blockIdx.x * 256u + threadIdx.x;
  if (i >= d.cum[12]) return;
  int t = 0;
  while (i >= d.cum[t + 1]) ++t;
  dst[i] = f2bf(d.src[t][i - d.cum[t]]);
}

// ---------------- embedding gather/build -> bf16 [2048 x 768] ----------------
__global__ void k_emb(const int* __restrict__ is_cat, const int* __restrict__ cat_idx,
                      const int* __restrict__ reg_idx, const float* __restrict__ reg_values,
                      const float* __restrict__ cat_table, const float* __restrict__ reg_table,
                      const float* __restrict__ reg_W, const float* __restrict__ reg_b,
                      short* __restrict__ out) {
  int i = blockIdx.x * 256 + threadIdx.x;  // exactly 2048*768 threads
  int n = i / EMBD, e = i - n * EMBD;
  float v;
  if (is_cat[n]) {
    v = cat_table[(long)cat_idx[n] * EMBD + e];
  } else {
    int r = reg_idx[n];
    if (e < 512) v = reg_table[r * 512 + e];
    else {
      int e2 = e - 512;
      v = reg_W[r * 256 + e2] * reg_values[n] + reg_b[r * 256 + e2];
    }
  }
  out[i] = f2bf(v);
}

// ---------------- S -> bf16 [16 x 512], rows 7..15 zeroed ---------------------
__global__ void k_sbuild(const float* __restrict__ S, short* __restrict__ out) {
  int i = blockIdx.x * 256 + threadIdx.x;  // 16*512
  int row = i >> 9;
  out[i] = (row < 7) ? f2bf(S[i]) : (short)0;
}

// ---------------- NT GEMM: C[M,N] = A[M,K] @ B[N,K]^T (+ epilogue) -----------
// One wave per 16x64 output tile. A,B bf16. out bf16 row-major [M,N].
// EPI 0: + bias[col]   (projections)
// EPI 1: + bias[row]   (transposed-V production: A=W, B=X, out=Vt[d][n])
// EPI 2: resid + relu(acc + bias[col])   (MAB feed-forward)
template <int EPI>
__global__ __launch_bounds__(64) void k_gemm(const short* __restrict__ A,
                                             const short* __restrict__ B,
                                             const float* __restrict__ bias,
                                             const short* __restrict__ resid,
                                             short* __restrict__ out,
                                             int M, int N, int K) {
  int l = threadIdx.x, l16 = l & 15, quad = l >> 4;
  int i0 = blockIdx.y * 16, n0 = blockIdx.x * 64;
  const short* arow = A + (i0 + l16) * K + quad * 8;
  const short* brow = B + (n0 + l16) * K + quad * 8;
  v4f acc[4];
  for (int t = 0; t < 4; ++t) acc[t] = (v4f){0.f, 0.f, 0.f, 0.f};
  for (int k = 0; k < K; k += 32) {
    v8s a = ldbf8(arow + k);
    acc[0] = MFMA(a, ldbf8(brow + k), acc[0]);
    acc[1] = MFMA(a, ldbf8(brow + 16 * K + k), acc[1]);
    acc[2] = MFMA(a, ldbf8(brow + 32 * K + k), acc[2]);
    acc[3] = MFMA(a, ldbf8(brow + 48 * K + k), acc[3]);
  }
  for (int t = 0; t < 4; ++t) {
    int col = n0 + t * 16 + l16;
    float bc = (EPI == 1) ? 0.f : bias[col];
    for (int r = 0; r < 4; ++r) {
      int row = i0 + quad * 4 + r;
      float v = acc[t][r];
      if (EPI == 0) v += bc;
      else if (EPI == 1) v += bias[row];
      else v = bf2f(resid[row * N + col]) + fmaxf(v + bc, 0.f);
      out[row * N + col] = f2bf(v);
    }
  }
}

// ---------------- flash attention (one wave per head x 16-query tile) --------
// Q,K: bf16 [Mq x 512] / [2048 x 512]; Vt: bf16 [512 x 2048] (transposed V).
// out[row, h*64+d] = Q[row, h*64+d] + softmax_j(Q_h K_h^T / sqrt(512)) V_h
__global__ __launch_bounds__(64) void k_flash(const short* __restrict__ Q,
                                              const short* __restrict__ Kp,
                                              const short* __restrict__ Vt,
                                              short* __restrict__ out) {
  __shared__ __align__(16) short P[16][40];  // 16x32 used; pad keeps 16B rows
  int h = blockIdx.y, i0 = blockIdx.x * 16;
  int l = threadIdx.x, l16 = l & 15, quad = l >> 4;
  int D0 = h * HD;
  const short* qrow = Q + (i0 + l16) * HID + D0 + quad * 8;
  v8s aq0 = ldbf8(qrow);
  v8s aq1 = ldbf8(qrow + 32);
  float m0[4], l0[4];
  v4f o[4];
  for (int r = 0; r < 4; ++r) { m0[r] = -1e30f; l0[r] = 0.f; }
  for (int t = 0; t < 4; ++t) o[t] = (v4f){0.f, 0.f, 0.f, 0.f};
  const float inv_scale = 0.04419417382415922f;  // 1/sqrt(512)

  for (int j0 = 0; j0 < NCTX; j0 += 32) {
    const short* kr0 = Kp + (j0 + l16) * HID + D0 + quad * 8;
    const short* kr1 = kr0 + 16 * HID;
    v4f s0 = (v4f){0.f, 0.f, 0.f, 0.f}, s1 = (v4f){0.f, 0.f, 0.f, 0.f};
    s0 = MFMA(aq0, ldbf8(kr0), s0);
    s0 = MFMA(aq1, ldbf8(kr0 + 32), s0);
    s1 = MFMA(aq0, ldbf8(kr1), s1);
    s1 = MFMA(aq1, ldbf8(kr1 + 32), s1);

    float mx[4];
    for (int r = 0; r < 4; ++r) {
      s0[r] *= inv_scale; s1[r] *= inv_scale;
      mx[r] = fmaxf(s0[r], s1[r]);
    }
    for (int msk = 1; msk < 16; msk <<= 1)
      for (int r = 0; r < 4; ++r) mx[r] = fmaxf(mx[r], __shfl_xor(mx[r], msk));

    float p0[4], p1[4], rs[4], alpha[4];
    for (int r = 0; r < 4; ++r) {
      float mn = fmaxf(m0[r], mx[r]);
      alpha[r] = __expf(m0[r] - mn);
      m0[r] = mn;
      p0[r] = __expf(s0[r] - mn);
      p1[r] = __expf(s1[r] - mn);
      rs[r] = p0[r] + p1[r];
    }
    for (int msk = 1; msk < 16; msk <<= 1)
      for (int r = 0; r < 4; ++r) rs[r] += __shfl_xor(rs[r], msk);
    for (int r = 0; r < 4; ++r) l0[r] = l0[r] * alpha[r] + rs[r];
    for (int t = 0; t < 4; ++t)
      for (int r = 0; r < 4; ++r) o[t][r] *= alpha[r];

    // P: C-layout -> A-layout via LDS (m120 pattern)
    __syncthreads();
    for (int r = 0; r < 4; ++r) {
      P[quad * 4 + r][l16] = f2bf(p0[r]);
      P[quad * 4 + r][16 + l16] = f2bf(p1[r]);
    }
    __syncthreads();
    v8s pa = *(const v8s*)&P[l16][quad * 8];

    for (int t = 0; t < 4; ++t) {
      v8s bv = ldbf8(Vt + (D0 + t * 16 + l16) * NCTX + j0 + quad * 8);
      o[t] = MFMA(pa, bv, o[t]);
    }
  }

  for (int t = 0; t < 4; ++t)
    for (int r = 0; r < 4; ++r) {
      int row = i0 + quad * 4 + r, col = D0 + t * 16 + l16;
      out[row * HID + col] = f2bf(bf2f(Q[row * HID + col]) + o[t][r] / l0[r]);
    }
}

// ---------------- final fc: out[j] = P[j,:] . fc_w + fc_b --------------------
__global__ __launch_bounds__(64) void k_fc(const short* __restrict__ P,
                                           const float* __restrict__ fcw,
                                           const float* __restrict__ fcb,
                                           float* __restrict__ out) {
  int j = blockIdx.x, l = threadIdx.x;
  float s = 0.f;
  int d0 = l * 8;
  for (int d = d0; d < d0 + 8; ++d) s += bf2f(P[j * HID + d]) * fcw[d];
  for (int msk = 1; msk < 64; msk <<= 1) s += __shfl_xor(s, msk);
  if (l == 0) out[j] = s + fcb[0];
}

// =============================================================================
extern "C" void kernel_launch(void* const* d_in, const int* in_sizes, int n_in,
                              void* d_out, int out_size, void* d_ws, size_t ws_size,
                              hipStream_t stream) {
  const int* is_cat = (const int*)d_in[0];
  const int* cat_idx = (const int*)d_in[1];
  const int* reg_idx = (const int*)d_in[2];
  const float* reg_values = (const float*)d_in[3];
  const float* cat_table = (const float*)d_in[4];
  const float* reg_table = (const float*)d_in[5];
  const float* reg_W = (const float*)d_in[6];
  const float* reg_b = (const float*)d_in[7];
  const float* q0_w = (const float*)d_in[8];  const float* q0_b = (const float*)d_in[9];
  const float* k0_w = (const float*)d_in[10]; const float* k0_b = (const float*)d_in[11];
  const float* v0_w = (const float*)d_in[12]; const float* v0_b = (const float*)d_in[13];
  const float* o0_w = (const float*)d_in[14]; const float* o0_b = (const float*)d_in[15];
  const float* qs_w = (const float*)d_in[16]; const float* qs_b = (const float*)d_in[17];
  const float* ks_w = (const float*)d_in[18]; const float* ks_b = (const float*)d_in[19];
  const float* vs_w = (const float*)d_in[20]; const float* vs_b = (const float*)d_in[21];
  const float* os_w = (const float*)d_in[22]; const float* os_b = (const float*)d_in[23];
  const float* S    = (const float*)d_in[24];
  const float* pq_w = (const float*)d_in[25]; const float* pq_b = (const float*)d_in[26];
  const float* pk_w = (const float*)d_in[27]; const float* pk_b = (const float*)d_in[28];
  const float* pv_w = (const float*)d_in[29]; const float* pv_b = (const float*)d_in[30];
  const float* po_w = (const float*)d_in[31]; const float* po_b = (const float*)d_in[32];
  const float* fc_w = (const float*)d_in[33]; const float* fc_b = (const float*)d_in[34];

  short* W = (short*)d_ws;
  // ---- workspace layout (offsets in shorts); total ~25.9 MB ----
  const unsigned OW_Q0 = 0;
  const unsigned OW_K0 = OW_Q0 + 512u * 768u;
  const unsigned OW_V0 = OW_K0 + 512u * 768u;
  const unsigned OW_O0 = OW_V0 + 512u * 768u;
  const unsigned OW_QS = OW_O0 + 512u * 512u;
  const unsigned OW_KS = OW_QS + 3u * 512u * 512u;
  const unsigned OW_VS = OW_KS + 3u * 512u * 512u;
  const unsigned OW_OS = OW_VS + 3u * 512u * 512u;
  const unsigned OW_PQ = OW_OS + 3u * 512u * 512u;
  const unsigned OW_PK = OW_PQ + 512u * 512u;
  const unsigned OW_PV = OW_PK + 512u * 512u;
  const unsigned OW_PO = OW_PV + 512u * 512u;
  const unsigned TOTW  = OW_PO + 512u * 512u;  // 5,636,096 shorts
  const unsigned OEMB = TOTW;
  const unsigned OXA  = OEMB + 2048u * 768u;
  const unsigned OXB  = OXA + 2048u * 512u;
  const unsigned OQP  = OXB + 2048u * 512u;
  const unsigned OKP  = OQP + 2048u * 512u;
  const unsigned OVT  = OKP + 2048u * 512u;
  const unsigned OOH  = OVT + 2048u * 512u;
  const unsigned OSB  = OOH + 2048u * 512u;
  const unsigned OQPP = OSB + 16u * 512u;
  const unsigned OOHP = OQPP + 16u * 512u;
  const unsigned OPP  = OOHP + 16u * 512u;

  // ---- weight conversion (one packed kernel) ----
  ConvDesc cd;
  const float* srcs[12] = {q0_w, k0_w, v0_w, o0_w, qs_w, ks_w, vs_w, os_w,
                           pq_w, pk_w, pv_w, po_w};
  const unsigned cums[13] = {OW_Q0, OW_K0, OW_V0, OW_O0, OW_QS, OW_KS, OW_VS,
                             OW_OS, OW_PQ, OW_PK, OW_PV, OW_PO, TOTW};
  for (int i = 0; i < 12; ++i) cd.src[i] = srcs[i];
  for (int i = 0; i < 13; ++i) cd.cum[i] = cums[i];
  k_convert<<<TOTW / 256, 256, 0, stream>>>(cd, W);

  k_emb<<<(2048 * 768) / 256, 256, 0, stream>>>(is_cat, cat_idx, reg_idx, reg_values,
                                                cat_table, reg_table, reg_W, reg_b,
                                                W + OEMB);
  k_sbuild<<<(16 * 512) / 256, 256, 0, stream>>>(S, W + OSB);

  // per-layer weight/bias tables
  const unsigned owq[4] = {OW_Q0, OW_QS, OW_QS + 262144u, OW_QS + 524288u};
  const unsigned owk[4] = {OW_K0, OW_KS, OW_KS + 262144u, OW_KS + 524288u};
  const unsigned owv[4] = {OW_V0, OW_VS, OW_VS + 262144u, OW_VS + 524288u};
  const unsigned owo[4] = {OW_O0, OW_OS, OW_OS + 262144u, OW_OS + 524288u};
  const float* bq[4] = {q0_b, qs_b, qs_b + 512, qs_b + 1024};
  const float* bk[4] = {k0_b, ks_b, ks_b + 512, ks_b + 1024};
  const float* bv[4] = {v0_b, vs_b, vs_b + 512, vs_b + 1024};
  const float* bo[4] = {o0_b, os_b, os_b + 512, os_b + 1024};
  const unsigned oxin[4]  = {OEMB, OXA, OXB, OXA};
  const unsigned oxout[4] = {OXA, OXB, OXA, OXB};
  const int kdim[4] = {768, 512, 512, 512};

  dim3 gp(512 / 64, 2048 / 16);   // projections / FF: [2048 x 512]
  dim3 gv(2048 / 64, 512 / 16);   // Vt: [512 x 2048]
  dim3 ga(2048 / 16, 8);          // flash: 128 q-tiles x 8 heads

  for (int lyr = 0; lyr < 4; ++lyr) {
    const short* X = W + oxin[lyr];
    short* Xout = W + oxout[lyr];
    int K = kdim[lyr];
    k_gemm<0><<<gp, 64, 0, stream>>>(X, W + owq[lyr], bq[lyr], nullptr, W + OQP, 2048, 512, K);
    k_gemm<0><<<gp, 64, 0, stream>>>(X, W + owk[lyr], bk[lyr], nullptr, W + OKP, 2048, 512, K);
    k_gemm<1><<<gv, 64, 0, stream>>>(W + owv[lyr], X, bv[lyr], nullptr, W + OVT, 512, 2048, K);
    k_flash<<<ga, 64, 0, stream>>>(W + OQP, W + OKP, W + OVT, W + OOH);
    k_gemm<2><<<gp, 64, 0, stream>>>(W + OOH, W + owo[lyr], bo[lyr], W + OOH, Xout, 2048, 512, 512);
  }

  // ---- PMA decoder: MAB(S_broadcast, x4) ----
  const short* X4 = W + OXB;
  k_gemm<0><<<dim3(8, 1), 64, 0, stream>>>(W + OSB, W + OW_PQ, pq_b, nullptr, W + OQPP, 16, 512, 512);
  k_gemm<0><<<gp, 64, 0, stream>>>(X4, W + OW_PK, pk_b, nullptr, W + OKP, 2048, 512, 512);
  k_gemm<1><<<gv, 64, 0, stream>>>(W + OW_PV, X4, pv_b, nullptr, W + OVT, 512, 2048, 512);
  k_flash<<<dim3(1, 8), 64, 0, stream>>>(W + OQPP, W + OKP, W + OVT, W + OOHP);
  k_gemm<2><<<dim3(8, 1), 64, 0, stream>>>(W + OOHP, W + OW_PO, po_b, W + OOHP, W + OPP, 16, 512, 512);
  k_fc<<<7, 64, 0, stream>>>(W + OPP, fc_w, fc_b, (float*)d_out);
}

// Round 2
// 833.793 us; speedup vs baseline: 1.4958x; 1.4958x over previous
//
#include <hip/hip_runtime.h>
#include <stdint.h>

// Set Transformer forward on gfx950. Round 2.
// N_KEYS=2048, EMB=768, HID=512, HEADS=8, head_dim=64, N_OUT=7.
// bf16 MFMA (16x16x32), fp32 accum. Flash attention: no-max softmax
// (scores bounded; exp2 arg clamped), LDS-shared K/V tiles per 4-wave block.

#define HID 512
#define EMBD 768
#define NCTX 2048
#define HD 64

typedef __attribute__((ext_vector_type(8))) short v8s;   // 8 x bf16
typedef __attribute__((ext_vector_type(4))) float v4f;   // MFMA accumulator

#define MFMA(a, b, c) __builtin_amdgcn_mfma_f32_16x16x32_bf16((a), (b), (c), 0, 0, 0)

__device__ __forceinline__ short f2bf(float f) {
  uint32_t u = __builtin_bit_cast(uint32_t, f);
  uint32_t r = (u + 0x7FFFu + ((u >> 16) & 1u)) >> 16;  // RNE
  return (short)r;
}
__device__ __forceinline__ float bf2f(short s) {
  uint32_t u = ((uint32_t)(uint16_t)s) << 16;
  return __builtin_bit_cast(float, u);
}
__device__ __forceinline__ v8s ldbf8(const short* p) { return *(const v8s*)p; }

// ---------------- weight f32 -> bf16 pre-conversion (packed, 20 segments) ----
struct ConvDesc {
  const float* src[20];
  unsigned cum[21];
};

__global__ void k_convert(ConvDesc d, short* __restrict__ dst) {
  unsigned i = blockIdx.x * 256u + threadIdx.x;
  if (i >= d.cum[20]) return;
  int t = 0;
  while (i >= d.cum[t + 1]) ++t;
  dst[i] = f2bf(d.src[t][i - d.cum[t]]);
}

// ---------------- embedding gather/build -> bf16 [2048 x 768] ----------------
__global__ void k_emb(const int* __restrict__ is_cat, const int* __restrict__ cat_idx,
                      const int* __restrict__ reg_idx, const float* __restrict__ reg_values,
                      const float* __restrict__ cat_table, const float* __restrict__ reg_table,
                      const float* __restrict__ reg_W, const float* __restrict__ reg_b,
                      short* __restrict__ out) {
  int i = blockIdx.x * 256 + threadIdx.x;  // exactly 2048*768 threads
  int n = i / EMBD, e = i - n * EMBD;
  float v;
  if (is_cat[n]) {
    v = cat_table[(long)cat_idx[n] * EMBD + e];
  } else {
    int r = reg_idx[n];
    if (e < 512) v = reg_table[r * 512 + e];
    else {
      int e2 = e - 512;
      v = reg_W[r * 256 + e2] * reg_values[n] + reg_b[r * 256 + e2];
    }
  }
  out[i] = f2bf(v);
}

// ---------------- S -> bf16 [64 x 512], rows 7..63 zeroed ---------------------
__global__ void k_sbuild(const float* __restrict__ S, short* __restrict__ out) {
  int i = blockIdx.x * 256 + threadIdx.x;  // 64*512
  int row = i >> 9;
  out[i] = (row < 7) ? f2bf(S[i]) : (short)0;
}

// ---------------- NT GEMM: C[M,N] = A[M,K] @ B[N,K]^T (+ epilogue) -----------
// One wave per 16x64 tile. K is compile-time for unroll/pipelining.
// EPI 0: + (col<512 ? biasA[col] : biasB[col-512])   (projections; QK fused)
// EPI 1: + biasA[row]                                (transposed-V production)
// EPI 2: resid + relu(acc + biasA[col])              (MAB feed-forward)
template <int EPI, int KK>
__global__ __launch_bounds__(64) void k_gemm(const short* __restrict__ A,
                                             const short* __restrict__ B,
                                             const float* __restrict__ biasA,
                                             const float* __restrict__ biasB,
                                             const short* __restrict__ resid,
                                             short* __restrict__ out, int N) {
  int l = threadIdx.x, l16 = l & 15, quad = l >> 4;
  int i0 = blockIdx.y * 16, n0 = blockIdx.x * 64;
  const short* arow = A + (i0 + l16) * KK + quad * 8;
  const short* brow = B + (n0 + l16) * KK + quad * 8;
  v4f acc[4];
  for (int t = 0; t < 4; ++t) acc[t] = (v4f){0.f, 0.f, 0.f, 0.f};
#pragma unroll 2
  for (int k = 0; k < KK; k += 32) {
    v8s a = ldbf8(arow + k);
    acc[0] = MFMA(a, ldbf8(brow + k), acc[0]);
    acc[1] = MFMA(a, ldbf8(brow + 16 * KK + k), acc[1]);
    acc[2] = MFMA(a, ldbf8(brow + 32 * KK + k), acc[2]);
    acc[3] = MFMA(a, ldbf8(brow + 48 * KK + k), acc[3]);
  }
  for (int t = 0; t < 4; ++t) {
    int col = n0 + t * 16 + l16;
    float bc;
    if (EPI == 0) bc = (col < 512) ? biasA[col] : biasB[col - 512];
    else if (EPI == 2) bc = biasA[col];
    else bc = 0.f;
    for (int r = 0; r < 4; ++r) {
      int row = i0 + quad * 4 + r;
      float v = acc[t][r];
      if (EPI == 0) v += bc;
      else if (EPI == 1) v += biasA[row];
      else v = bf2f(resid[row * N + col]) + fmaxf(v + bc, 0.f);
      out[row * N + col] = f2bf(v);
    }
  }
}

// ---------------- flash attention, 4 waves/block sharing K/V via LDS ---------
// Block: 256 thr = 4 waves, each wave one 16-query tile; block covers 64 queries.
// Q rows at qstride; K rows at kstride; Vt is [512][2048] (row = hid dim).
// out[row, D0+d] = Q[row, D0+d] + softmax_j(QK^T/sqrt(512)) V   (no-max softmax)
__global__ __launch_bounds__(256) void k_flash(const short* __restrict__ Q, int qstride,
                                               const short* __restrict__ Kp, int kstride,
                                               const short* __restrict__ Vt,
                                               short* __restrict__ out) {
  __shared__ __align__(16) short Kt[64 * 64];   // XOR-swizzled 16B chunks
  __shared__ __align__(16) short Vtl[64 * 64];
  __shared__ __align__(16) short P[4][16 * 72]; // per-wave P, stride 72 (2-way free)
  const int tid = threadIdx.x;
  const int wave = tid >> 6, l = tid & 63, l16 = l & 15, quad = l >> 4;
  const int D0 = blockIdx.y * HD;
  const int i0 = blockIdx.x * 64 + wave * 16;

  const short* qrow = Q + (i0 + l16) * qstride + D0 + quad * 8;
  const v8s aq0 = ldbf8(qrow);
  const v8s aq1 = ldbf8(qrow + 32);

  // staging: thread covers row sr, chunks sc0 and sc0+4 (16B each) of K and Vt tiles
  const int sr = tid >> 2, sc0 = tid & 3, sc1 = sc0 + 4;
  const short* kg = Kp + sr * kstride + D0;
  const short* vg = Vt + (D0 + sr) * NCTX;
  short* kl0 = &Kt[(sr * 8 + (sc0 ^ (sr & 7))) * 8];
  short* kl1 = &Kt[(sr * 8 + (sc1 ^ (sr & 7))) * 8];
  short* vl0 = &Vtl[(sr * 8 + (sc0 ^ (sr & 7))) * 8];
  short* vl1 = &Vtl[(sr * 8 + (sc1 ^ (sr & 7))) * 8];

  v4f o[4];
  float lsum[4];
  for (int t = 0; t < 4; ++t) o[t] = (v4f){0.f, 0.f, 0.f, 0.f};
  for (int r = 0; r < 4; ++r) lsum[r] = 0.f;

  // register double-buffer of the staged tiles
  v8s pk0 = ldbf8(kg + sc0 * 8), pk1 = ldbf8(kg + sc1 * 8);
  v8s pv0 = ldbf8(vg + sc0 * 8), pv1 = ldbf8(vg + sc1 * 8);

  const float C2 = 0.06375872f;  // log2(e)/sqrt(512): exp(s/sqrt512)=exp2(s*C2)

  for (int j0 = 0; j0 < NCTX; j0 += 64) {
    __syncthreads();                       // prev iter's LDS reads done
    *(v8s*)kl0 = pk0; *(v8s*)kl1 = pk1;
    *(v8s*)vl0 = pv0; *(v8s*)vl1 = pv1;
    __syncthreads();                       // tiles visible
    int jn = j0 + 64;
    if (jn < NCTX) {                       // prefetch next tiles (overlaps compute)
      pk0 = ldbf8(kg + jn * kstride + sc0 * 8);
      pk1 = ldbf8(kg + jn * kstride + sc1 * 8);
      pv0 = ldbf8(vg + jn + sc0 * 8);
      pv1 = ldbf8(vg + jn + sc1 * 8);
    }
    // QK^T for 4 key-tiles of 16
    v4f s[4];
    for (int kt = 0; kt < 4; ++kt) {
      int R = kt * 16 + l16;
      v8s kb0 = *(const v8s*)&Kt[(R * 8 + (quad ^ (R & 7))) * 8];
      v8s kb1 = *(const v8s*)&Kt[(R * 8 + ((quad + 4) ^ (R & 7))) * 8];
      v4f t0 = (v4f){0.f, 0.f, 0.f, 0.f};
      t0 = MFMA(aq0, kb0, t0);
      s[kt] = MFMA(aq1, kb1, t0);
    }
    // exp (no running max), per-lane denominator accumulation, P -> LDS
    short* pw = &P[wave][0];
    for (int kt = 0; kt < 4; ++kt)
      for (int r = 0; r < 4; ++r) {
        float p = exp2f(fminf(s[kt][r] * C2, 40.f));
        lsum[r] += p;
        pw[(quad * 4 + r) * 72 + kt * 16 + l16] = f2bf(p);
      }
    __syncthreads();                       // P visible (C-layout -> A-layout)
    v8s pa0 = *(const v8s*)&pw[l16 * 72 + quad * 8];
    v8s pa1 = *(const v8s*)&pw[l16 * 72 + 32 + quad * 8];
    for (int t = 0; t < 4; ++t) {
      int R = t * 16 + l16;
      v8s bv0 = *(const v8s*)&Vtl[(R * 8 + (quad ^ (R & 7))) * 8];
      v8s bv1 = *(const v8s*)&Vtl[(R * 8 + ((quad + 4) ^ (R & 7))) * 8];
      o[t] = MFMA(pa0, bv0, o[t]);
      o[t] = MFMA(pa1, bv1, o[t]);
    }
  }
  // one cross-lane denominator reduce (cols of a row live in lanes quad*16+0..15)
  for (int r = 0; r < 4; ++r) {
    lsum[r] += __shfl_xor(lsum[r], 1);
    lsum[r] += __shfl_xor(lsum[r], 2);
    lsum[r] += __shfl_xor(lsum[r], 4);
    lsum[r] += __shfl_xor(lsum[r], 8);
  }
  for (int r = 0; r < 4; ++r) {
    float inv = 1.f / lsum[r];
    int row = i0 + quad * 4 + r;
    for (int t = 0; t < 4; ++t) {
      int col = D0 + t * 16 + l16;
      out[row * HID + col] = f2bf(bf2f(Q[row * qstride + col]) + o[t][r] * inv);
    }
  }
}

// ---------------- final fc: out[j] = P[j,:] . fc_w + fc_b --------------------
__global__ __launch_bounds__(64) void k_fc(const short* __restrict__ P,
                                           const float* __restrict__ fcw,
                                           const float* __restrict__ fcb,
                                           float* __restrict__ out) {
  int j = blockIdx.x, l = threadIdx.x;
  float s = 0.f;
  int d0 = l * 8;
  for (int d = d0; d < d0 + 8; ++d) s += bf2f(P[j * HID + d]) * fcw[d];
  for (int msk = 1; msk < 64; msk <<= 1) s += __shfl_xor(s, msk);
  if (l == 0) out[j] = s + fcb[0];
}

// =============================================================================
extern "C" void kernel_launch(void* const* d_in, const int* in_sizes, int n_in,
                              void* d_out, int out_size, void* d_ws, size_t ws_size,
                              hipStream_t stream) {
  const int* is_cat = (const int*)d_in[0];
  const int* cat_idx = (const int*)d_in[1];
  const int* reg_idx = (const int*)d_in[2];
  const float* reg_values = (const float*)d_in[3];
  const float* cat_table = (const float*)d_in[4];
  const float* reg_table = (const float*)d_in[5];
  const float* reg_W = (const float*)d_in[6];
  const float* reg_b = (const float*)d_in[7];
  const float* q0_w = (const float*)d_in[8];  const float* q0_b = (const float*)d_in[9];
  const float* k0_w = (const float*)d_in[10]; const float* k0_b = (const float*)d_in[11];
  const float* v0_w = (const float*)d_in[12]; const float* v0_b = (const float*)d_in[13];
  const float* o0_w = (const float*)d_in[14]; const float* o0_b = (const float*)d_in[15];
  const float* qs_w = (const float*)d_in[16]; const float* qs_b = (const float*)d_in[17];
  const float* ks_w = (const float*)d_in[18]; const float* ks_b = (const float*)d_in[19];
  const float* vs_w = (const float*)d_in[20]; const float* vs_b = (const float*)d_in[21];
  const float* os_w = (const float*)d_in[22]; const float* os_b = (const float*)d_in[23];
  const float* S    = (const float*)d_in[24];
  const float* pq_w = (const float*)d_in[25]; const float* pq_b = (const float*)d_in[26];
  const float* pk_w = (const float*)d_in[27]; const float* pk_b = (const float*)d_in[28];
  const float* pv_w = (const float*)d_in[29]; const float* pv_b = (const float*)d_in[30];
  const float* po_w = (const float*)d_in[31]; const float* po_b = (const float*)d_in[32];
  const float* fc_w = (const float*)d_in[33]; const float* fc_b = (const float*)d_in[34];

  short* W = (short*)d_ws;

  // ---- packed bf16 weight layout (shorts). Per layer: [wq;wk] adjacent, wv, wo.
  const unsigned OWQK[4] = {0u, 1441792u, 2490368u, 3538944u};
  const unsigned OWV[4]  = {786432u, 1966080u, 3014656u, 4063232u};
  const unsigned OWO[4]  = {1179648u, 2228224u, 3276800u, 4325376u};
  const unsigned OPQW = 4587520u, OPKW = 4849664u, OPVW = 5111808u, OPOW = 5373952u;
  const unsigned TOTW = 5636096u;
  // ---- activations
  const unsigned OEMB = TOTW;                     // 2048x768
  const unsigned OXA  = OEMB + 1572864u;          // 2048x512
  const unsigned OXB  = OXA + 1048576u;           // 2048x512
  const unsigned OQK  = OXB + 1048576u;           // 2048x1024 (Q | K fused)
  const unsigned OVT  = OQK + 2097152u;           // 512x2048 (V transposed)
  const unsigned OOH  = OVT + 1048576u;           // 2048x512 (attn out)
  const unsigned OSB  = OOH + 1048576u;           // 64x512  (S padded)
  const unsigned OQPP = OSB + 32768u;             // 64x512  (PMA Qp)
  const unsigned OKPP = OQPP + 32768u;            // 2048x512 (PMA Kp)
  const unsigned OOHP = OKPP + 1048576u;          // 64x512  (PMA attn out)
  const unsigned OPP  = OOHP + 32768u;            // 16x512  (PMA final)

  // ---- weight conversion (20 segments; per-layer q,k adjacent in dst) ----
  ConvDesc cd;
  const float* srcs[20] = {
      q0_w, k0_w, v0_w, o0_w,
      qs_w, ks_w, vs_w, os_w,
      qs_w + 262144, ks_w + 262144, vs_w + 262144, os_w + 262144,
      qs_w + 524288, ks_w + 524288, vs_w + 524288, os_w + 524288,
      pq_w, pk_w, pv_w, po_w};
  const unsigned cums[21] = {0u,       393216u,  786432u,  1179648u, 1441792u,
                             1703936u, 1966080u, 2228224u, 2490368u, 2752512u,
                             3014656u, 3276800u, 3538944u, 3801088u, 4063232u,
                             4325376u, 4587520u, 4849664u, 5111808u, 5373952u,
                             5636096u};
  for (int i = 0; i < 20; ++i) cd.src[i] = srcs[i];
  for (int i = 0; i < 21; ++i) cd.cum[i] = cums[i];
  k_convert<<<(TOTW + 255) / 256, 256, 0, stream>>>(cd, W);

  k_emb<<<(2048 * 768) / 256, 256, 0, stream>>>(is_cat, cat_idx, reg_idx, reg_values,
                                                cat_table, reg_table, reg_W, reg_b,
                                                W + OEMB);
  k_sbuild<<<(64 * 512) / 256, 256, 0, stream>>>(S, W + OSB);

  const float* bq[4] = {q0_b, qs_b, qs_b + 512, qs_b + 1024};
  const float* bk[4] = {k0_b, ks_b, ks_b + 512, ks_b + 1024};
  const float* bv[4] = {v0_b, vs_b, vs_b + 512, vs_b + 1024};
  const float* bo[4] = {o0_b, os_b, os_b + 512, os_b + 1024};
  const unsigned oxin[4]  = {OEMB, OXA, OXB, OXA};
  const unsigned oxout[4] = {OXA, OXB, OXA, OXB};

  dim3 gqk(16, 128);  // [2048 x 1024]
  dim3 gv(32, 32);    // [512 x 2048]
  dim3 go(8, 128);    // [2048 x 512]
  dim3 gf(32, 8);     // flash: 32 query-blocks x 8 heads

  for (int l = 0; l < 4; ++l) {
    const short* X = W + oxin[l];
    short* Xout = W + oxout[l];
    if (l == 0) {
      k_gemm<0, 768><<<gqk, 64, 0, stream>>>(X, W + OWQK[0], bq[0], bk[0], nullptr, W + OQK, 1024);
      k_gemm<1, 768><<<gv, 64, 0, stream>>>(W + OWV[0], X, bv[0], bv[0], nullptr, W + OVT, 2048);
    } else {
      k_gemm<0, 512><<<gqk, 64, 0, stream>>>(X, W + OWQK[l], bq[l], bk[l], nullptr, W + OQK, 1024);
      k_gemm<1, 512><<<gv, 64, 0, stream>>>(W + OWV[l], X, bv[l], bv[l], nullptr, W + OVT, 2048);
    }
    k_flash<<<gf, 256, 0, stream>>>(W + OQK, 1024, W + OQK + 512, 1024, W + OVT, W + OOH);
    k_gemm<2, 512><<<go, 64, 0, stream>>>(W + OOH, W + OWO[l], bo[l], bo[l], W + OOH, Xout, 512);
  }

  // ---- PMA decoder ----
  k_gemm<0, 512><<<dim3(8, 4), 64, 0, stream>>>(W + OSB, W + OPQW, pq_b, pq_b, nullptr, W + OQPP, 512);
  k_gemm<0, 512><<<dim3(8, 128), 64, 0, stream>>>(W + OXB, W + OPKW, pk_b, pk_b, nullptr, W + OKPP, 512);
  k_gemm<1, 512><<<dim3(32, 32), 64, 0, stream>>>(W + OPVW, W + OXB, pv_b, pv_b, nullptr, W + OVT, 2048);
  k_flash<<<dim3(1, 8), 256, 0, stream>>>(W + OQPP, 512, W + OKPP, 512, W + OVT, W + OOHP);
  k_gemm<2, 512><<<dim3(8, 1), 64, 0, stream>>>(W + OOHP, W + OPOW, po_b, po_b, W + OOHP, W + OPP, 512);
  k_fc<<<7, 64, 0, stream>>>(W + OPP, fc_w, fc_b, (float*)d_out);
}

// Round 3
// 742.324 us; speedup vs baseline: 1.6801x; 1.1232x over previous
//
#include <hip/hip_runtime.h>
#include <stdint.h>

// Set Transformer forward on gfx950. Round 3.
// Changes vs R2: flash attention split-K=4 (no-max softmax -> linear combine),
// P-barrier removed (wave-private LDS), fp32 partial O + combine kernel;
// GEMM 32x64 per-wave tiles with unroll 4 (-40% L2 traffic, more ILP).

#define HID 512
#define EMBD 768
#define NCTX 2048
#define HD 64

typedef __attribute__((ext_vector_type(8))) short v8s;   // 8 x bf16
typedef __attribute__((ext_vector_type(4))) float v4f;   // MFMA accumulator

#define MFMA(a, b, c) __builtin_amdgcn_mfma_f32_16x16x32_bf16((a), (b), (c), 0, 0, 0)

__device__ __forceinline__ short f2bf(float f) {
  uint32_t u = __builtin_bit_cast(uint32_t, f);
  uint32_t r = (u + 0x7FFFu + ((u >> 16) & 1u)) >> 16;  // RNE
  return (short)r;
}
__device__ __forceinline__ float bf2f(short s) {
  uint32_t u = ((uint32_t)(uint16_t)s) << 16;
  return __builtin_bit_cast(float, u);
}
__device__ __forceinline__ v8s ldbf8(const short* p) { return *(const v8s*)p; }

// ---------------- weight f32 -> bf16 pre-conversion (packed, 20 segments) ----
struct ConvDesc {
  const float* src[20];
  unsigned cum[21];
};

__global__ void k_convert(ConvDesc d, short* __restrict__ dst) {
  unsigned i = blockIdx.x * 256u + threadIdx.x;
  if (i >= d.cum[20]) return;
  int t = 0;
  while (i >= d.cum[t + 1]) ++t;
  dst[i] = f2bf(d.src[t][i - d.cum[t]]);
}

// ---------------- embedding gather/build -> bf16 [2048 x 768] ----------------
__global__ void k_emb(const int* __restrict__ is_cat, const int* __restrict__ cat_idx,
                      const int* __restrict__ reg_idx, const float* __restrict__ reg_values,
                      const float* __restrict__ cat_table, const float* __restrict__ reg_table,
                      const float* __restrict__ reg_W, const float* __restrict__ reg_b,
                      short* __restrict__ out) {
  int i = blockIdx.x * 256 + threadIdx.x;  // exactly 2048*768 threads
  int n = i / EMBD, e = i - n * EMBD;
  float v;
  if (is_cat[n]) {
    v = cat_table[(long)cat_idx[n] * EMBD + e];
  } else {
    int r = reg_idx[n];
    if (e < 512) v = reg_table[r * 512 + e];
    else {
      int e2 = e - 512;
      v = reg_W[r * 256 + e2] * reg_values[n] + reg_b[r * 256 + e2];
    }
  }
  out[i] = f2bf(v);
}

// ---------------- S -> bf16 [64 x 512], rows 7..63 zeroed ---------------------
__global__ void k_sbuild(const float* __restrict__ S, short* __restrict__ out) {
  int i = blockIdx.x * 256 + threadIdx.x;  // 64*512
  int row = i >> 9;
  out[i] = (row < 7) ? f2bf(S[i]) : (short)0;
}

// ---------------- NT GEMM: C[M,N] = A[M,K] @ B[N,K]^T (+ epilogue) -----------
// One wave per 32x64 tile (2 row-groups x 4 col-tiles, 8 indep MFMA chains).
// EPI 0: + (col<512 ? biasA[col] : biasB[col-512])   (projections; QK fused)
// EPI 1: + biasA[row]                                (transposed-V production)
// EPI 2: resid + relu(acc + biasA[col])              (MAB feed-forward)
template <int EPI, int KK>
__global__ __launch_bounds__(64) void k_gemm(const short* __restrict__ A,
                                             const short* __restrict__ B,
                                             const float* __restrict__ biasA,
                                             const float* __restrict__ biasB,
                                             const short* __restrict__ resid,
                                             short* __restrict__ out, int N) {
  int l = threadIdx.x, l16 = l & 15, quad = l >> 4;
  int i0 = blockIdx.y * 32, n0 = blockIdx.x * 64;
  const short* a0p = A + (i0 + l16) * KK + quad * 8;
  const short* a1p = a0p + 16 * KK;
  const short* bp = B + (n0 + l16) * KK + quad * 8;
  v4f acc[2][4];
  for (int g = 0; g < 2; ++g)
    for (int t = 0; t < 4; ++t) acc[g][t] = (v4f){0.f, 0.f, 0.f, 0.f};
#pragma unroll 4
  for (int k = 0; k < KK; k += 32) {
    v8s a0 = ldbf8(a0p + k);
    v8s a1 = ldbf8(a1p + k);
#pragma unroll
    for (int t = 0; t < 4; ++t) {
      v8s b = ldbf8(bp + t * 16 * KK + k);
      acc[0][t] = MFMA(a0, b, acc[0][t]);
      acc[1][t] = MFMA(a1, b, acc[1][t]);
    }
  }
  for (int g = 0; g < 2; ++g)
    for (int t = 0; t < 4; ++t) {
      int col = n0 + t * 16 + l16;
      float bc;
      if (EPI == 0) bc = (col < 512) ? biasA[col] : biasB[col - 512];
      else if (EPI == 2) bc = biasA[col];
      else bc = 0.f;
      for (int r = 0; r < 4; ++r) {
        int row = i0 + g * 16 + quad * 4 + r;
        float v = acc[g][t][r];
        if (EPI == 0) v += bc;
        else if (EPI == 1) v += biasA[row];
        else v = bf2f(resid[row * N + col]) + fmaxf(v + bc, 0.f);
        out[row * N + col] = f2bf(v);
      }
    }
}

// ---------------- flash attention, split-K=4, 4 waves/block ------------------
// Block: 256 thr = 4 waves, each wave a 16-query tile; z = key-chunk of 512.
// Writes UNNORMALIZED fp32 partial O and per-row partial denominators.
__global__ __launch_bounds__(256) void k_flash(const short* __restrict__ Q, int qstride,
                                               const short* __restrict__ Kp, int kstride,
                                               const short* __restrict__ Vt,
                                               float* __restrict__ opart,
                                               float* __restrict__ lspart) {
  __shared__ __align__(16) short Kt[64 * 64];   // XOR-swizzled 16B chunks
  __shared__ __align__(16) short Vtl[64 * 64];
  __shared__ __align__(16) short P[4][16 * 72];
  const int tid = threadIdx.x;
  const int wave = tid >> 6, l = tid & 63, l16 = l & 15, quad = l >> 4;
  const int h = blockIdx.y, D0 = h * HD;
  const int i0 = blockIdx.x * 64 + wave * 16;
  const int z = blockIdx.z, jbase = z * (NCTX / 4);

  const short* qrow = Q + (i0 + l16) * qstride + D0 + quad * 8;
  const v8s aq0 = ldbf8(qrow);
  const v8s aq1 = ldbf8(qrow + 32);

  const int sr = tid >> 2, sc0 = tid & 3, sc1 = sc0 + 4;
  const short* kg = Kp + (jbase + sr) * kstride + D0;
  const short* vg = Vt + (D0 + sr) * NCTX + jbase;
  short* kl0 = &Kt[(sr * 8 + (sc0 ^ (sr & 7))) * 8];
  short* kl1 = &Kt[(sr * 8 + (sc1 ^ (sr & 7))) * 8];
  short* vl0 = &Vtl[(sr * 8 + (sc0 ^ (sr & 7))) * 8];
  short* vl1 = &Vtl[(sr * 8 + (sc1 ^ (sr & 7))) * 8];

  v4f o[4];
  float lsum[4];
  for (int t = 0; t < 4; ++t) o[t] = (v4f){0.f, 0.f, 0.f, 0.f};
  for (int r = 0; r < 4; ++r) lsum[r] = 0.f;

  v8s pk0 = ldbf8(kg + sc0 * 8), pk1 = ldbf8(kg + sc1 * 8);
  v8s pv0 = ldbf8(vg + sc0 * 8), pv1 = ldbf8(vg + sc1 * 8);

  const float C2 = 0.06375872f;  // log2(e)/sqrt(512)

  for (int j0 = 0; j0 < NCTX / 4; j0 += 64) {
    __syncthreads();                       // prev iter's tile reads done
    *(v8s*)kl0 = pk0; *(v8s*)kl1 = pk1;
    *(v8s*)vl0 = pv0; *(v8s*)vl1 = pv1;
    __syncthreads();                       // tiles visible
    int jn = j0 + 64;
    if (jn < NCTX / 4) {
      pk0 = ldbf8(kg + jn * kstride + sc0 * 8);
      pk1 = ldbf8(kg + jn * kstride + sc1 * 8);
      pv0 = ldbf8(vg + jn + sc0 * 8);
      pv1 = ldbf8(vg + jn + sc1 * 8);
    }
    v4f s[4];
#pragma unroll
    for (int kt = 0; kt < 4; ++kt) {
      int R = kt * 16 + l16;
      v8s kb0 = *(const v8s*)&Kt[(R * 8 + (quad ^ (R & 7))) * 8];
      v8s kb1 = *(const v8s*)&Kt[(R * 8 + ((quad + 4) ^ (R & 7))) * 8];
      v4f t0 = (v4f){0.f, 0.f, 0.f, 0.f};
      t0 = MFMA(aq0, kb0, t0);
      s[kt] = MFMA(aq1, kb1, t0);
    }
    short* pw = &P[wave][0];
#pragma unroll
    for (int kt = 0; kt < 4; ++kt)
      for (int r = 0; r < 4; ++r) {
        float p = exp2f(fminf(s[kt][r] * C2, 40.f));
        lsum[r] += p;
        pw[(quad * 4 + r) * 72 + kt * 16 + l16] = f2bf(p);
      }
    // P is wave-private: wave-local LDS ordering is enough (no block barrier)
    asm volatile("s_waitcnt lgkmcnt(0)" ::: "memory");
    v8s pa0 = *(const v8s*)&pw[l16 * 72 + quad * 8];
    v8s pa1 = *(const v8s*)&pw[l16 * 72 + 32 + quad * 8];
#pragma unroll
    for (int t = 0; t < 4; ++t) {
      int R = t * 16 + l16;
      v8s bv0 = *(const v8s*)&Vtl[(R * 8 + (quad ^ (R & 7))) * 8];
      v8s bv1 = *(const v8s*)&Vtl[(R * 8 + ((quad + 4) ^ (R & 7))) * 8];
      o[t] = MFMA(pa0, bv0, o[t]);
      o[t] = MFMA(pa1, bv1, o[t]);
    }
  }
  for (int r = 0; r < 4; ++r) {
    lsum[r] += __shfl_xor(lsum[r], 1);
    lsum[r] += __shfl_xor(lsum[r], 2);
    lsum[r] += __shfl_xor(lsum[r], 4);
    lsum[r] += __shfl_xor(lsum[r], 8);
  }
  float* ob = opart + (size_t)z * (NCTX * HID);
  for (int t = 0; t < 4; ++t)
    for (int r = 0; r < 4; ++r)
      ob[(i0 + quad * 4 + r) * HID + D0 + t * 16 + l16] = o[t][r];
  if (l16 == 0)
    for (int r = 0; r < 4; ++r)
      lspart[z * (8 * NCTX) + h * NCTX + i0 + quad * 4 + r] = lsum[r];
}

// ---------------- combine partials: out = bf16(Qresid + (sum O_p)/(sum l_p)) --
__global__ void k_combine(const float* __restrict__ op, const float* __restrict__ ls,
                          const short* __restrict__ Qr, int qstride,
                          short* __restrict__ out) {
  const int PS = NCTX * HID;
  int i = blockIdx.x * 256 + threadIdx.x;  // M*512 threads
  int row = i >> 9, col = i & 511, h = col >> 6;
  float o = op[i] + op[i + PS] + op[i + 2 * PS] + op[i + 3 * PS];
  int li = h * NCTX + row;
  float d = ls[li] + ls[li + 8 * NCTX] + ls[li + 16 * NCTX] + ls[li + 24 * NCTX];
  out[i] = f2bf(bf2f(Qr[row * qstride + col]) + o / d);
}

// ---------------- final fc: out[j] = P[j,:] . fc_w + fc_b --------------------
__global__ __launch_bounds__(64) void k_fc(const short* __restrict__ P,
                                           const float* __restrict__ fcw,
                                           const float* __restrict__ fcb,
                                           float* __restrict__ out) {
  int j = blockIdx.x, l = threadIdx.x;
  float s = 0.f;
  int d0 = l * 8;
  for (int d = d0; d < d0 + 8; ++d) s += bf2f(P[j * HID + d]) * fcw[d];
  for (int msk = 1; msk < 64; msk <<= 1) s += __shfl_xor(s, msk);
  if (l == 0) out[j] = s + fcb[0];
}

// =============================================================================
extern "C" void kernel_launch(void* const* d_in, const int* in_sizes, int n_in,
                              void* d_out, int out_size, void* d_ws, size_t ws_size,
                              hipStream_t stream) {
  const int* is_cat = (const int*)d_in[0];
  const int* cat_idx = (const int*)d_in[1];
  const int* reg_idx = (const int*)d_in[2];
  const float* reg_values = (const float*)d_in[3];
  const float* cat_table = (const float*)d_in[4];
  const float* reg_table = (const float*)d_in[5];
  const float* reg_W = (const float*)d_in[6];
  const float* reg_b = (const float*)d_in[7];
  const float* q0_w = (const float*)d_in[8];  const float* q0_b = (const float*)d_in[9];
  const float* k0_w = (const float*)d_in[10]; const float* k0_b = (const float*)d_in[11];
  const float* v0_w = (const float*)d_in[12]; const float* v0_b = (const float*)d_in[13];
  const float* o0_w = (const float*)d_in[14]; const float* o0_b = (const float*)d_in[15];
  const float* qs_w = (const float*)d_in[16]; const float* qs_b = (const float*)d_in[17];
  const float* ks_w = (const float*)d_in[18]; const float* ks_b = (const float*)d_in[19];
  const float* vs_w = (const float*)d_in[20]; const float* vs_b = (const float*)d_in[21];
  const float* os_w = (const float*)d_in[22]; const float* os_b = (const float*)d_in[23];
  const float* S    = (const float*)d_in[24];
  const float* pq_w = (const float*)d_in[25]; const float* pq_b = (const float*)d_in[26];
  const float* pk_w = (const float*)d_in[27]; const float* pk_b = (const float*)d_in[28];
  const float* pv_w = (const float*)d_in[29]; const float* pv_b = (const float*)d_in[30];
  const float* po_w = (const float*)d_in[31]; const float* po_b = (const float*)d_in[32];
  const float* fc_w = (const float*)d_in[33]; const float* fc_b = (const float*)d_in[34];

  short* W = (short*)d_ws;

  // ---- packed bf16 weights (shorts). Per layer: [wq;wk] adjacent, wv, wo.
  const unsigned OWQK[4] = {0u, 1441792u, 2490368u, 3538944u};
  const unsigned OWV[4]  = {786432u, 1966080u, 3014656u, 4063232u};
  const unsigned OWO[4]  = {1179648u, 2228224u, 3276800u, 4325376u};
  const unsigned OPQW = 4587520u, OPKW = 4849664u, OPVW = 5111808u, OPOW = 5373952u;
  const unsigned TOTW = 5636096u;
  // ---- bf16 activations
  const unsigned OEMB = TOTW;              // 2048x768
  const unsigned OXA  = OEMB + 1572864u;   // 2048x512
  const unsigned OXB  = OXA + 1048576u;    // 2048x512
  const unsigned OQK  = OXB + 1048576u;    // 2048x1024 (Q|K fused)
  const unsigned OVT  = OQK + 2097152u;    // 512x2048 (V transposed)
  const unsigned OOH  = OVT + 1048576u;    // 2048x512 (attn out)
  const unsigned OSB  = OOH + 1048576u;    // 64x512 (S padded)
  const unsigned OQPP = OSB + 32768u;      // 64x512
  const unsigned OKPP = OQPP + 32768u;     // 2048x512
  const unsigned OOHP = OKPP + 1048576u;   // 64x512
  const unsigned OPP  = OOHP + 32768u;     // 32x512 (PMA final, padded)
  const unsigned OF32 = OPP + 32768u;      // fp32 region starts here (even)
  float* F = (float*)(W + OF32);           // opart: 4 x [2048x512] fp32
  float* LS = F + 4u * 1048576u;           // lspart: 4 x [8x2048] fp32

  // ---- weight conversion (20 segments; per-layer q,k adjacent in dst) ----
  ConvDesc cd;
  const float* srcs[20] = {
      q0_w, k0_w, v0_w, o0_w,
      qs_w, ks_w, vs_w, os_w,
      qs_w + 262144, ks_w + 262144, vs_w + 262144, os_w + 262144,
      qs_w + 524288, ks_w + 524288, vs_w + 524288, os_w + 524288,
      pq_w, pk_w, pv_w, po_w};
  const unsigned cums[21] = {0u,       393216u,  786432u,  1179648u, 1441792u,
                             1703936u, 1966080u, 2228224u, 2490368u, 2752512u,
                             3014656u, 3276800u, 3538944u, 3801088u, 4063232u,
                             4325376u, 4587520u, 4849664u, 5111808u, 5373952u,
                             5636096u};
  for (int i = 0; i < 20; ++i) cd.src[i] = srcs[i];
  for (int i = 0; i < 21; ++i) cd.cum[i] = cums[i];
  k_convert<<<(TOTW + 255) / 256, 256, 0, stream>>>(cd, W);

  k_emb<<<(2048 * 768) / 256, 256, 0, stream>>>(is_cat, cat_idx, reg_idx, reg_values,
                                                cat_table, reg_table, reg_W, reg_b,
                                                W + OEMB);
  k_sbuild<<<(64 * 512) / 256, 256, 0, stream>>>(S, W + OSB);

  const float* bq[4] = {q0_b, qs_b, qs_b + 512, qs_b + 1024};
  const float* bk[4] = {k0_b, ks_b, ks_b + 512, ks_b + 1024};
  const float* bv[4] = {v0_b, vs_b, vs_b + 512, vs_b + 1024};
  const float* bo[4] = {o0_b, os_b, os_b + 512, os_b + 1024};
  const unsigned oxin[4]  = {OEMB, OXA, OXB, OXA};
  const unsigned oxout[4] = {OXA, OXB, OXA, OXB};

  dim3 gqk(16, 64);   // [2048 x 1024], 32x64 tiles
  dim3 gv(32, 16);    // [512 x 2048]
  dim3 go(8, 64);     // [2048 x 512]
  dim3 gf(32, 8, 4);  // flash: 32 q-blocks x 8 heads x 4 key-chunks

  for (int l = 0; l < 4; ++l) {
    const short* X = W + oxin[l];
    short* Xout = W + oxout[l];
    if (l == 0) {
      k_gemm<0, 768><<<gqk, 64, 0, stream>>>(X, W + OWQK[0], bq[0], bk[0], nullptr, W + OQK, 1024);
      k_gemm<1, 768><<<gv, 64, 0, stream>>>(W + OWV[0], X, bv[0], bv[0], nullptr, W + OVT, 2048);
    } else {
      k_gemm<0, 512><<<gqk, 64, 0, stream>>>(X, W + OWQK[l], bq[l], bk[l], nullptr, W + OQK, 1024);
      k_gemm<1, 512><<<gv, 64, 0, stream>>>(W + OWV[l], X, bv[l], bv[l], nullptr, W + OVT, 2048);
    }
    k_flash<<<gf, 256, 0, stream>>>(W + OQK, 1024, W + OQK + 512, 1024, W + OVT, F, LS);
    k_combine<<<(2048 * 512) / 256, 256, 0, stream>>>(F, LS, W + OQK, 1024, W + OOH);
    k_gemm<2, 512><<<go, 64, 0, stream>>>(W + OOH, W + OWO[l], bo[l], bo[l], W + OOH, Xout, 512);
  }

  // ---- PMA decoder ----
  k_gemm<0, 512><<<dim3(8, 2), 64, 0, stream>>>(W + OSB, W + OPQW, pq_b, pq_b, nullptr, W + OQPP, 512);
  k_gemm<0, 512><<<dim3(8, 64), 64, 0, stream>>>(W + OXB, W + OPKW, pk_b, pk_b, nullptr, W + OKPP, 512);
  k_gemm<1, 512><<<dim3(32, 16), 64, 0, stream>>>(W + OPVW, W + OXB, pv_b, pv_b, nullptr, W + OVT, 2048);
  k_flash<<<dim3(1, 8, 4), 256, 0, stream>>>(W + OQPP, 512, W + OKPP, 512, W + OVT, F, LS);
  k_combine<<<(16 * 512) / 256, 256, 0, stream>>>(F, LS, W + OQPP, 512, W + OOHP);
  k_gemm<2, 512><<<dim3(8, 1), 64, 0, stream>>>(W + OOHP, W + OPOW, po_b, po_b, W + OOHP, W + OPP, 512);
  k_fc<<<7, 64, 0, stream>>>(W + OPP, fc_w, fc_b, (float*)d_out);
}